// Round 13
// baseline (45.644 us; speedup 1.0000x reference)
//
#include <hip/hip_runtime.h>

#define NB   64
#define LSEQ 8192
#define NW   8190
#define HD   90
#define AMPF 28.5f

typedef _Float16 half8  __attribute__((ext_vector_type(8)));
typedef float    f32x16 __attribute__((ext_vector_type(16)));
typedef __fp16   fp16x2 __attribute__((ext_vector_type(2)));

union FragU { uint4 u; half8 h; };

__device__ __forceinline__ unsigned pk2(float a, float b) {
  fp16x2 v = __builtin_amdgcn_cvt_pkrtz(a, b);
  return __builtin_bit_cast(unsigned, v);
}
__device__ __forceinline__ unsigned pkmax0(unsigned w) {
  unsigned r;
  asm("v_pk_max_f16 %0, %1, %2" : "=v"(r) : "v"(w), "v"(0u));
  return r;
}

// ---------------- weight fragment pre-pack (unchanged layout) ----------------
__global__ void dnpu_pack(const float* __restrict__ W1, const float* __restrict__ b1,
                          const float* __restrict__ W2, const float* __restrict__ b2,
                          const float* __restrict__ W3, const float* __restrict__ b3,
                          const float* __restrict__ W4, const float* __restrict__ b4,
                          const float* __restrict__ W5, const float* __restrict__ b5,
                          const float* __restrict__ W6, const float* __restrict__ b6,
                          uint4* __restrict__ frags) {
  int tid = blockIdx.x * blockDim.x + threadIdx.x;
  if (tid >= 81 * 64) return;
  int f = tid >> 6, lane = tid & 63;
  int n = lane & 31, g = lane >> 5;
  const float* W; const float* bias; int t2, ks, kin, nout;
  if (f < 3) {
    W = W1; bias = b1; t2 = f; ks = 0; kin = 7; nout = HD;
  } else if (f < 75) {
    int q = f - 3; int L = q / 18; int r = q % 18;
    t2 = r / 6; ks = r % 6; kin = HD; nout = HD;
    W    = (L == 0) ? W2 : (L == 1) ? W3 : (L == 2) ? W4 : W5;
    bias = (L == 0) ? b2 : (L == 1) ? b3 : (L == 2) ? b4 : b5;
  } else {
    W = W6; bias = b6; t2 = 0; ks = f - 75; kin = HD; nout = 1;
  }
  int row = 32 * t2 + n;
  FragU u;
#pragma unroll
  for (int i = 0; i < 8; ++i) {
    int k = 16 * ks + 8 * g + i;
    float val = 0.f;
    if (row < nout) {
      if (k < kin)       val = W[k * nout + row];
      else if (k == kin) val = bias[row];
    }
    if (row == HD && k == kin && f < 75) val = 1.0f;  // bias-propagation row
    u.h[i] = (_Float16)val;
  }
  frags[f * 64 + lane] = u.u;
}

// ---- per-u transition (unchanged math) ----
__device__ __forceinline__ void trans_u(const f32x16& a, uint4& b0, uint4& b1) {
  unsigned p00 = pkmax0(pk2(a[0],  a[1]));
  unsigned p10 = pkmax0(pk2(a[2],  a[3]));
  unsigned p01 = pkmax0(pk2(a[4],  a[5]));
  unsigned p11 = pkmax0(pk2(a[6],  a[7]));
  unsigned p02 = pkmax0(pk2(a[8],  a[9]));
  unsigned p12 = pkmax0(pk2(a[10], a[11]));
  unsigned p03 = pkmax0(pk2(a[12], a[13]));
  unsigned p13 = pkmax0(pk2(a[14], a[15]));
  asm("v_permlane32_swap_b32 %0, %1" : "+v"(p00), "+v"(p01));
  asm("v_permlane32_swap_b32 %0, %1" : "+v"(p10), "+v"(p11));
  b0 = make_uint4(p00, p10, p01, p11);
  asm("v_permlane32_swap_b32 %0, %1" : "+v"(p02), "+v"(p03));
  asm("v_permlane32_swap_b32 %0, %1" : "+v"(p12), "+v"(p13));
  b1 = make_uint4(p02, p12, p03, p13);
}

// 6-MFMA cluster: u-block row slice against one tile's B-frags
__device__ __forceinline__ f32x16 cluster(const uint4* __restrict__ src, int u, int lane,
                                          const uint4 (&B)[6]) {
  f32x16 a = (f32x16)(0.f);
#pragma unroll
  for (int ks = 0; ks < 6; ++ks) {
    FragU Af; Af.u = src[(u * 6 + ks) * 64 + lane];
    a = __builtin_amdgcn_mfma_f32_32x32x16_f16(
          Af.h, __builtin_bit_cast(half8, B[ks]), a, 0, 0, 0);
  }
  return a;
}

// one hidden 96x96 layer over 2 tiles, SOFTWARE-PIPELINED:
// cluster(k+1) is issued before trans(k) so the 6-MFMA chain (independent)
// overlaps the previous cluster's 20-op VALU transition. Bin -> Bout
// ping-pong removes all end-of-layer register copies.
__device__ __forceinline__ void layer_pipe(const uint4* __restrict__ src, int lane,
                                           const uint4 (&B0)[6], const uint4 (&B1)[6],
                                           uint4 (&O0)[6], uint4 (&O1)[6]) {
  f32x16 a00 = cluster(src, 0, lane, B0);
  f32x16 a10 = cluster(src, 0, lane, B1);
  f32x16 a01 = cluster(src, 1, lane, B0);
  trans_u(a00, O0[0], O0[1]);
  f32x16 a11 = cluster(src, 1, lane, B1);
  trans_u(a10, O1[0], O1[1]);
  f32x16 a02 = cluster(src, 2, lane, B0);
  trans_u(a01, O0[2], O0[3]);
  f32x16 a12 = cluster(src, 2, lane, B1);
  trans_u(a11, O1[2], O1[3]);
  trans_u(a02, O0[4], O0[5]);
  trans_u(a12, O1[4], O1[5]);
}

// ---------------- main kernel ----------------
// NOTE (measured R5/R6): launch_bounds min-waves caps VGPR at 256/min_waves;
// min=4 -> 64 regs -> 1.1 GB scratch spill. Keep min=2 (cap 256 regs on gfx9:
// 512-pool/2). R13: software-pipelined transitions; 256-thread blocks with
// 36.9 KB two-buffer restage so ~160-reg waves still get 3 blocks/CU.
__global__ __launch_bounds__(256, 2)
void dnpu_mfma(const float* __restrict__ x, const float* __restrict__ cv,
               const uint4* __restrict__ frags, float* __restrict__ out) {
  __shared__ uint4 lfr[2][18 * 64];          // 2 x 18,432 B = 36,864 B
  const int tid  = threadIdx.x;
  const int lane = tid & 63, wid = tid >> 6;
  const int g = lane >> 5, c = lane & 31;
  const int b = blockIdx.y;

  // stage L2 -> buf0, L3 -> buf1
  for (int i = tid; i < 18 * 64; i += 256) {
    lfr[0][i] = frags[3 * 64 + i];
    lfr[1][i] = frags[21 * 64 + i];
  }
  __syncthreads();

  const float c0 = cv[0], c1 = cv[1], c2 = cv[2], c3 = cv[3];
  const float* xr = x + (size_t)b * LSEQ;
  const int rowbase0 = blockIdx.x * 256 + wid * 64;   // 2 tiles x 32 windows/wave

  uint4 Bw[2][6], Bv[2][6];

  // ---- layer 1 -> Bw ----
#pragma unroll
  for (int t = 0; t < 2; ++t) {
    const int w  = rowbase0 + t * 32 + c;
    const int xi = (w < LSEQ - 3) ? w : (LSEQ - 3);
    const float x0 = xr[xi], x1 = xr[xi + 1], x2 = xr[xi + 2];
    half8 B1;
#pragma unroll
    for (int i = 0; i < 8; ++i) B1[i] = (_Float16)0.f;
    if (g == 0) {
      B1[0] = (_Float16)c0; B1[1] = (_Float16)c1;
      B1[2] = (_Float16)x0; B1[3] = (_Float16)x1; B1[4] = (_Float16)x2;
      B1[5] = (_Float16)c2; B1[6] = (_Float16)c3; B1[7] = (_Float16)1.0f;
    }
#pragma unroll
    for (int t2 = 0; t2 < 3; ++t2) {
      FragU Af; Af.u = frags[t2 * 64 + lane];
      f32x16 a = __builtin_amdgcn_mfma_f32_32x32x16_f16(Af.h, B1, (f32x16)(0.f), 0, 0, 0);
      trans_u(a, Bw[t][2 * t2], Bw[t][2 * t2 + 1]);
    }
  }

  // ---- L2: Bw->Bv (buf0) ----
  layer_pipe(&lfr[0][0], lane, Bw[0], Bw[1], Bv[0], Bv[1]);
  __syncthreads();                                        // done reading buf0
  for (int i = tid; i < 18 * 64; i += 256) lfr[0][i] = frags[39 * 64 + i];  // L4
  __syncthreads();
  // ---- L3: Bv->Bw (buf1) ----
  layer_pipe(&lfr[1][0], lane, Bv[0], Bv[1], Bw[0], Bw[1]);
  __syncthreads();                                        // done reading buf1
  for (int i = tid; i < 18 * 64; i += 256) lfr[1][i] = frags[57 * 64 + i];  // L5
  __syncthreads();
  // ---- L4: Bw->Bv (buf0) ----
  layer_pipe(&lfr[0][0], lane, Bw[0], Bw[1], Bv[0], Bv[1]);
  // ---- L5: Bv->Bw (buf1) ----
  layer_pipe(&lfr[1][0], lane, Bv[0], Bv[1], Bw[0], Bw[1]);

  // ---- layer 6: 96 -> 1, then * AMP ----
  {
    FragU Af6[6];
#pragma unroll
    for (int ks = 0; ks < 6; ++ks) Af6[ks].u = frags[(75 + ks) * 64 + lane];
#pragma unroll
    for (int t = 0; t < 2; ++t) {
      f32x16 a = (f32x16)(0.f);
#pragma unroll
      for (int ks = 0; ks < 6; ++ks)
        a = __builtin_amdgcn_mfma_f32_32x32x16_f16(
              Af6[ks].h, __builtin_bit_cast(half8, Bw[t][ks]), a, 0, 0, 0);
      if (g == 0) {
        const int row = rowbase0 + t * 32 + c;
        if (row < NW) out[(size_t)b * NW + row] = a[0] * AMPF;
      }
    }
  }
}

extern "C" void kernel_launch(void* const* d_in, const int* in_sizes, int n_in,
                              void* d_out, int out_size, void* d_ws, size_t ws_size,
                              hipStream_t stream) {
  const float* x  = (const float*)d_in[0];
  const float* cv = (const float*)d_in[1];
  const float* W1 = (const float*)d_in[2];
  const float* b1 = (const float*)d_in[3];
  const float* W2 = (const float*)d_in[4];
  const float* b2 = (const float*)d_in[5];
  const float* W3 = (const float*)d_in[6];
  const float* b3 = (const float*)d_in[7];
  const float* W4 = (const float*)d_in[8];
  const float* b4 = (const float*)d_in[9];
  const float* W5 = (const float*)d_in[10];
  const float* b5 = (const float*)d_in[11];
  const float* W6 = (const float*)d_in[12];
  const float* b6 = (const float*)d_in[13];
  float* out = (float*)d_out;
  uint4* frags = (uint4*)d_ws;   // 81 * 64 * 16 B = 82,944 B

  hipLaunchKernelGGL(dnpu_pack, dim3(21), dim3(256), 0, stream,
                     W1, b1, W2, b2, W3, b3, W4, b4, W5, b5, W6, b6, frags);
  // 8192 windows: 32 blocks x (4 waves * 64 windows)
  hipLaunchKernelGGL(dnpu_mfma, dim3(32, NB), dim3(256), 0, stream,
                     x, cv, frags, out);
}